// Round 1
// baseline (187.506 us; speedup 1.0000x reference)
//
#include <hip/hip_runtime.h>
#include <hip/hip_bf16.h>

// Problem constants (fixed by setup_inputs)
#define N_ 4
#define M_ 64
#define C_ 768
#define HF 48
#define WF 48
#define HI 768
#define WI 768
#define R_ 8
#define NM (N_*M_)

// ws layout:
//   [0)            int bbox[NM][4]       (ymin, ymax, xmin, xmax)   4096 B
//   [4096)         float boxes_feat[NM][4]                          4096 B
//   [8192)         uint8 masks_small[NM][48*48]                     2359296 B
#define WS_BBOX_OFF   0
#define WS_BF_OFF     4096
#define WS_MS_OFF     8192
#define MS_PER_MAP    (HF*WF)   // 2304

__global__ void init_ws_kernel(int* __restrict__ bbox, unsigned int* __restrict__ ms32) {
    int idx = blockIdx.x * 256 + threadIdx.x;
    int total32 = NM * MS_PER_MAP / 4;   // 589824
    if (idx < total32) ms32[idx] = 0u;
    if (idx < NM) {
        bbox[idx*4 + 0] = 1 << 30;   // ymin sentinel
        bbox[idx*4 + 1] = -1;        // ymax
        bbox[idx*4 + 2] = 1 << 30;   // xmin
        bbox[idx*4 + 3] = -1;        // xmax
    }
}

// Phase 1: stream the 604MB mask tensor once. For each nonzero pixel:
//  - atomic bbox update for its (n,m)
//  - idempotent store of 1 into masks_small at the unique (i,j) whose 15x15
//    dilation window covers (y,x)  [window(15) < stride(16) => at most one]
__global__ void scan_masks_kernel(const float4* __restrict__ masks,
                                  int* __restrict__ bbox,
                                  unsigned char* __restrict__ msmall) {
    const int nm = blockIdx.y;
    const int t  = blockIdx.x * 256 + threadIdx.x;      // vec4 index within map: 0..147455
    const float4 v = masks[(size_t)nm * (HI*WI/4) + t];
    if (!(v.x > 0.f || v.y > 0.f || v.z > 0.f || v.w > 0.f)) return;

    const int y  = t / (WI/4);          // 0..767
    const int x4 = (t % (WI/4)) * 4;
    int* bb = bbox + nm*4;
    unsigned char* ms = msmall + nm * MS_PER_MAP;

    float vv[4] = {v.x, v.y, v.z, v.w};
    #pragma unroll
    for (int k = 0; k < 4; ++k) {
        if (vv[k] > 0.f) {
            const int x = x4 + k;
            atomicMin(&bb[0], y);
            atomicMax(&bb[1], y);
            atomicMin(&bb[2], x);
            atomicMax(&bb[3], x);
            const int i = (y + 7) >> 4;
            const int j = (x + 7) >> 4;
            if (((y & 15) != 8) && i < HF && ((x & 15) != 8) && j < WF)
                ms[i*WF + j] = 1;
        }
    }
}

// Phase 2a: boxes (output 0), roi_masks (output 1), boxes_feat (ws) — 1 block, 256 threads.
__global__ void boxes_masks_kernel(const int* __restrict__ bbox,
                                   const unsigned char* __restrict__ msmall,
                                   float* __restrict__ boxes_feat,
                                   float* __restrict__ out) {
    const int nm = threadIdx.x;    // 0..255
    const int* bb = bbox + nm*4;
    const int ymin = bb[0], ymax = bb[1], xmin = bb[2], xmax = bb[3];

    float bf0, bf1, bf2, bf3;
    if (ymax < 0) {             // empty mask
        bf0 = bf1 = bf2 = bf3 = 0.f;
    } else {
        // dilate(+-7) then expand(+-1) then clip == +-8 clipped
        const int x1 = max(xmin - 8, 0);
        const int y1 = max(ymin - 8, 0);
        const int x2 = min(xmax + 8, WI - 1);
        const int y2 = min(ymax + 8, HI - 1);
        bf0 = (float)x1 * 0.0625f;    // * (Hf/Hi) = /16, exact
        bf1 = (float)y1 * 0.0625f;
        bf2 = (float)x2 * 0.0625f;
        bf3 = (float)y2 * 0.0625f;
    }
    boxes_feat[nm*4+0] = bf0; boxes_feat[nm*4+1] = bf1;
    boxes_feat[nm*4+2] = bf2; boxes_feat[nm*4+3] = bf3;
    // output 0: boxes / Hf
    out[nm*4+0] = bf0 / (float)HF;
    out[nm*4+1] = bf1 / (float)HF;
    out[nm*4+2] = bf2 / (float)HF;
    out[nm*4+3] = bf3 / (float)HF;

    // output 1: roi_masks  (crop of masks_small with int coords)
    const int x1i = max((int)floorf(bf0), 0);
    const int y1i = max((int)floorf(bf1), 0);
    const int x2i = min((int)floorf(bf2), WF - 1);
    const int y2i = min((int)floorf(bf3), HF - 1);
    const int h = y2i - y1i + 1;
    const int w = x2i - x1i + 1;
    const unsigned char* ms = msmall + nm * MS_PER_MAP;

    float crop[R_][R_];
    float sum = 0.f;
    int yi[R_], xi[R_];
    #pragma unroll
    for (int r = 0; r < R_; ++r) {
        yi[r] = y1i + (r * h) / R_;
        xi[r] = x1i + (r * w) / R_;
    }
    #pragma unroll
    for (int r = 0; r < R_; ++r)
        #pragma unroll
        for (int s = 0; s < R_; ++s) {
            float cv = (float)ms[yi[r]*WF + xi[s]];
            crop[r][s] = cv;
            sum += cv;
        }
    float* rm = out + NM*4 + nm * (R_*R_);
    #pragma unroll
    for (int r = 0; r < R_; ++r)
        #pragma unroll
        for (int s = 0; s < R_; ++s)
            rm[r*R_ + s] = (sum > 0.f) ? crop[r][s] : 1.f;
}

// Phase 2b: roi-align + mask-multiply -> emb (output 2).
// Block = 256 threads = 4 channels x 64 positions; grid = (C/4, NM).
// The 64 bilinear positions/weights are shared across all C channels -> LDS.
__global__ void roi_feat_kernel(const float* __restrict__ feat,
                                const float* __restrict__ boxes_feat,
                                const float* __restrict__ roi_masks,  // in d_out
                                float* __restrict__ emb) {
    const int nm = blockIdx.y;
    const int n  = nm >> 6;         // /M_
    const int cg = blockIdx.x;      // 0..191
    const int tid = threadIdx.x;

    __shared__ float s_w00[64], s_w01[64], s_w10[64], s_w11[64], s_m[64];
    __shared__ int   s_a00[64], s_a01[64], s_a10[64], s_a11[64];

    if (tid < 64) {
        const float x1  = boxes_feat[nm*4+0];
        const float y1f = boxes_feat[nm*4+1];
        const float x2  = boxes_feat[nm*4+2];
        const float y2f = boxes_feat[nm*4+3];
        const float bw = fmaxf(x2 - x1, 1.f) * (1.f / R_);
        const float bh = fmaxf(y2f - y1f, 1.f) * (1.f / R_);
        const int r = tid >> 3, s = tid & 7;
        float py = y1f + ((float)r + 0.5f) * bh;
        float px = x1  + ((float)s + 0.5f) * bw;
        // (validity condition is always true for these box ranges; clip per ref)
        py = fminf(fmaxf(py, 0.f), (float)(HF - 1));
        px = fminf(fmaxf(px, 0.f), (float)(WF - 1));
        const int y0 = (int)floorf(py);
        const int x0 = (int)floorf(px);
        const int y1i = min(y0 + 1, HF - 1);
        const int x1i = min(x0 + 1, WF - 1);
        const float ly = py - (float)y0, lx = px - (float)x0;
        const float hy = 1.f - ly,       hx = 1.f - lx;
        s_w00[tid] = hy * hx;  s_w01[tid] = hy * lx;
        s_w10[tid] = ly * hx;  s_w11[tid] = ly * lx;
        s_a00[tid] = y0 * WF + x0;   s_a01[tid] = y0 * WF + x1i;
        s_a10[tid] = y1i * WF + x0;  s_a11[tid] = y1i * WF + x1i;
        s_m[tid] = roi_masks[nm * 64 + tid];
    }
    __syncthreads();

    const int c   = cg * 4 + (tid >> 6);
    const int pos = tid & 63;
    const float* f = feat + ((size_t)(n * C_ + c)) * (HF * WF);
    const float v00 = f[s_a00[pos]], v01 = f[s_a01[pos]];
    const float v10 = f[s_a10[pos]], v11 = f[s_a11[pos]];
    const float val = s_w00[pos]*v00 + s_w01[pos]*v01 + s_w10[pos]*v10 + s_w11[pos]*v11;
    emb[((size_t)nm * C_ + c) * 64 + pos] = val * s_m[pos];
}

extern "C" void kernel_launch(void* const* d_in, const int* in_sizes, int n_in,
                              void* d_out, int out_size, void* d_ws, size_t ws_size,
                              hipStream_t stream) {
    const float* feat  = (const float*)d_in[0];   // (4,768,48,48)
    const float* masks = (const float*)d_in[1];   // (4,64,768,768)
    float* out = (float*)d_out;

    char* ws = (char*)d_ws;
    int* bbox            = (int*)(ws + WS_BBOX_OFF);
    float* boxes_feat    = (float*)(ws + WS_BF_OFF);
    unsigned char* msmall = (unsigned char*)(ws + WS_MS_OFF);

    // init
    init_ws_kernel<<<(NM*MS_PER_MAP/4 + 255)/256, 256, 0, stream>>>(bbox, (unsigned int*)msmall);

    // phase 1: stream masks
    dim3 g1(HI*WI/4/256, NM);   // (576, 256)
    scan_masks_kernel<<<g1, 256, 0, stream>>>((const float4*)masks, bbox, msmall);

    // phase 2a: boxes + roi_masks
    boxes_masks_kernel<<<1, NM, 0, stream>>>(bbox, msmall, boxes_feat, out);

    // phase 2b: emb
    const float* roi_masks = out + NM*4;
    float* emb = out + NM*4 + NM*R_*R_;
    dim3 g2(C_/4, NM);          // (192, 256)
    roi_feat_kernel<<<g2, 256, 0, stream>>>(feat, boxes_feat, roi_masks, emb);
}

// Round 2
// 168.204 us; speedup vs baseline: 1.1148x; 1.1148x over previous
//
#include <hip/hip_runtime.h>
#include <hip/hip_bf16.h>

// Problem constants (fixed by setup_inputs)
#define N_ 4
#define M_ 64
#define C_ 768
#define HF 48
#define WF 48
#define HI 768
#define WI 768
#define R_ 8
#define NM (N_*M_)

// ws layout:
//   [0)      int bbox[NM][4] (ymin,ymax,xmin,xmax)
//   [4096)   float boxes_feat[NM][4]
//   [8192)   uint8 masks_small[NM][48*48]
#define WS_BBOX_OFF   0
#define WS_BF_OFF     4096
#define WS_MS_OFF     8192
#define MS_PER_MAP    (HF*WF)   // 2304

#define VEC4_PER_MAP  (HI*WI/4)                       // 147456
#define SCAN_LPT      16                              // float4 loads per thread
#define SCAN_BX       (VEC4_PER_MAP/(256*SCAN_LPT))   // 36

typedef float f32x4 __attribute__((ext_vector_type(4)));

__global__ void init_ws_kernel(int* __restrict__ bbox, unsigned int* __restrict__ ms32) {
    int idx = blockIdx.x * 256 + threadIdx.x;
    int total32 = NM * MS_PER_MAP / 4;   // 147456
    if (idx < total32) ms32[idx] = 0u;
    if (idx < NM) {
        bbox[idx*4 + 0] = 1 << 30;   // ymin sentinel
        bbox[idx*4 + 1] = -1;        // ymax
        bbox[idx*4 + 2] = 1 << 30;   // xmin
        bbox[idx*4 + 3] = -1;        // xmax
    }
}

// Phase 1: stream the 604MB mask tensor once (nontemporal — zero reuse).
// window(15) < stride(16) => each nonzero pixel maps to at most one
// masks_small cell: i=(y+7)>>4 valid iff (y&15)!=8 && i<48.
__global__ void scan_masks_kernel(const f32x4* __restrict__ masks,
                                  int* __restrict__ bbox,
                                  unsigned char* __restrict__ msmall) {
    const int nm = blockIdx.y;
    const size_t map_off = (size_t)nm * VEC4_PER_MAP;
    const int chunk = blockIdx.x * (256 * SCAN_LPT);
    int* bb = bbox + nm * 4;
    unsigned char* ms = msmall + nm * MS_PER_MAP;

    #pragma unroll
    for (int k = 0; k < SCAN_LPT; ++k) {
        const int t = chunk + k * 256 + threadIdx.x;
        const f32x4 v = __builtin_nontemporal_load(masks + map_off + t);
        if (v.x > 0.f || v.y > 0.f || v.z > 0.f || v.w > 0.f) {
            const int y  = t / (WI/4);
            const int x4 = (t - y * (WI/4)) * 4;
            const float vv[4] = {v.x, v.y, v.z, v.w};
            #pragma unroll
            for (int q = 0; q < 4; ++q) {
                if (vv[q] > 0.f) {
                    const int x = x4 + q;
                    atomicMin(&bb[0], y);
                    atomicMax(&bb[1], y);
                    atomicMin(&bb[2], x);
                    atomicMax(&bb[3], x);
                    const int i = (y + 7) >> 4;
                    const int j = (x + 7) >> 4;
                    if (((y & 15) != 8) && i < HF && ((x & 15) != 8) && j < WF)
                        ms[i*WF + j] = 1;
                }
            }
        }
    }
}

// Phase 2a: boxes (output 0) + roi_masks (output 1) + boxes_feat (ws).
// One wave (64 threads) per (n,m).
__global__ void boxes_masks_kernel(const int* __restrict__ bbox,
                                   const unsigned char* __restrict__ msmall,
                                   float* __restrict__ boxes_feat,
                                   float* __restrict__ out) {
    const int nm = blockIdx.x;
    const int tid = threadIdx.x;   // 0..63
    const int ymin = bbox[nm*4+0], ymax = bbox[nm*4+1];
    const int xmin = bbox[nm*4+2], xmax = bbox[nm*4+3];

    float bf0, bf1, bf2, bf3;
    if (ymax < 0) {              // empty mask
        bf0 = bf1 = bf2 = bf3 = 0.f;
    } else {
        // dilate(+-7) + expand(+-1) + clip == +-8 clipped; *(Hf/Hi) = /16 exact
        bf0 = (float)max(xmin - 8, 0) * 0.0625f;
        bf1 = (float)max(ymin - 8, 0) * 0.0625f;
        bf2 = (float)min(xmax + 8, WI - 1) * 0.0625f;
        bf3 = (float)min(ymax + 8, HI - 1) * 0.0625f;
    }
    if (tid == 0) {
        boxes_feat[nm*4+0] = bf0; boxes_feat[nm*4+1] = bf1;
        boxes_feat[nm*4+2] = bf2; boxes_feat[nm*4+3] = bf3;
        out[nm*4+0] = bf0 * (1.f/HF);
        out[nm*4+1] = bf1 * (1.f/HF);
        out[nm*4+2] = bf2 * (1.f/HF);
        out[nm*4+3] = bf3 * (1.f/HF);
    }

    // roi_masks crop
    const int x1i = max((int)floorf(bf0), 0);
    const int y1i = max((int)floorf(bf1), 0);
    const int x2i = min((int)floorf(bf2), WF - 1);
    const int y2i = min((int)floorf(bf3), HF - 1);
    const int h = y2i - y1i + 1;
    const int w = x2i - x1i + 1;
    const int r = tid >> 3, s = tid & 7;
    const int yi = y1i + (r * h) / R_;
    const int xi = x1i + (s * w) / R_;
    const float cv = (float)msmall[nm*MS_PER_MAP + yi*WF + xi];
    const bool nonzero = __any(cv > 0.f);
    out[NM*4 + nm*64 + tid] = nonzero ? cv : 1.f;
}

// Phase 2b: roi-align + mask-multiply -> emb (output 2).
// Block = 256 threads = 4 channel-pairs x 64 positions; grid = (C/8, NM).
// 64 bilinear positions/weights shared across all C channels -> LDS.
__global__ void roi_feat_kernel(const float* __restrict__ feat,
                                const float* __restrict__ boxes_feat,
                                const float* __restrict__ roi_masks,
                                float* __restrict__ emb) {
    const int nm = blockIdx.y;
    const int n  = nm >> 6;
    const int cg = blockIdx.x;      // 0..95
    const int tid = threadIdx.x;

    __shared__ float s_w[4][64];
    __shared__ int   s_a[4][64];
    __shared__ float s_m[64];

    if (tid < 64) {
        const float x1  = boxes_feat[nm*4+0];
        const float y1f = boxes_feat[nm*4+1];
        const float x2  = boxes_feat[nm*4+2];
        const float y2f = boxes_feat[nm*4+3];
        const float bw = fmaxf(x2 - x1, 1.f) * (1.f / R_);
        const float bh = fmaxf(y2f - y1f, 1.f) * (1.f / R_);
        const int r = tid >> 3, s = tid & 7;
        float py = y1f + ((float)r + 0.5f) * bh;
        float px = x1  + ((float)s + 0.5f) * bw;
        py = fminf(fmaxf(py, 0.f), (float)(HF - 1));
        px = fminf(fmaxf(px, 0.f), (float)(WF - 1));
        const int y0 = (int)floorf(py);
        const int x0 = (int)floorf(px);
        const int y1i = min(y0 + 1, HF - 1);
        const int x1i = min(x0 + 1, WF - 1);
        const float ly = py - (float)y0, lx = px - (float)x0;
        const float hy = 1.f - ly,       hx = 1.f - lx;
        s_w[0][tid] = hy * hx;  s_w[1][tid] = hy * lx;
        s_w[2][tid] = ly * hx;  s_w[3][tid] = ly * lx;
        s_a[0][tid] = y0 * WF + x0;   s_a[1][tid] = y0 * WF + x1i;
        s_a[2][tid] = y1i * WF + x0;  s_a[3][tid] = y1i * WF + x1i;
        s_m[tid] = roi_masks[nm * 64 + tid];
    }
    __syncthreads();

    const int pos = tid & 63;
    const int c0  = cg * 8 + (tid >> 6) * 2;
    const float w0 = s_w[0][pos], w1 = s_w[1][pos], w2 = s_w[2][pos], w3 = s_w[3][pos];
    const int   a0 = s_a[0][pos], a1 = s_a[1][pos], a2 = s_a[2][pos], a3 = s_a[3][pos];
    const float m  = s_m[pos];
    const float* f0 = feat + ((size_t)(n * C_ + c0)) * (HF * WF);
    const float* f1 = f0 + HF * WF;
    const float r0 = w0*f0[a0] + w1*f0[a1] + w2*f0[a2] + w3*f0[a3];
    const float r1 = w0*f1[a0] + w1*f1[a1] + w2*f1[a2] + w3*f1[a3];
    float* e = emb + ((size_t)nm * C_ + c0) * 64 + pos;
    e[0]  = r0 * m;
    e[64] = r1 * m;
}

extern "C" void kernel_launch(void* const* d_in, const int* in_sizes, int n_in,
                              void* d_out, int out_size, void* d_ws, size_t ws_size,
                              hipStream_t stream) {
    const float* feat  = (const float*)d_in[0];   // (4,768,48,48)
    const float* masks = (const float*)d_in[1];   // (4,64,768,768)
    float* out = (float*)d_out;

    char* ws = (char*)d_ws;
    int* bbox             = (int*)(ws + WS_BBOX_OFF);
    float* boxes_feat     = (float*)(ws + WS_BF_OFF);
    unsigned char* msmall = (unsigned char*)(ws + WS_MS_OFF);

    // init
    init_ws_kernel<<<(NM*MS_PER_MAP/4 + 255)/256, 256, 0, stream>>>(bbox, (unsigned int*)msmall);

    // phase 1: stream masks
    dim3 g1(SCAN_BX, NM);   // (36, 256)
    scan_masks_kernel<<<g1, 256, 0, stream>>>((const f32x4*)masks, bbox, msmall);

    // phase 2a: boxes + roi_masks (one wave per nm)
    boxes_masks_kernel<<<NM, 64, 0, stream>>>(bbox, msmall, boxes_feat, out);

    // phase 2b: emb
    const float* roi_masks = out + NM*4;
    float* emb = out + NM*4 + NM*R_*R_;
    dim3 g2(C_/8, NM);      // (96, 256)
    roi_feat_kernel<<<g2, 256, 0, stream>>>(feat, boxes_feat, roi_masks, emb);
}

// Round 3
// 157.227 us; speedup vs baseline: 1.1926x; 1.0698x over previous
//
#include <hip/hip_runtime.h>
#include <hip/hip_bf16.h>

// Problem constants (fixed by setup_inputs)
#define N_ 4
#define M_ 64
#define C_ 768
#define HF 48
#define WF 48
#define HWF (HF*WF)   // 2304
#define HI 768
#define WI 768
#define R_ 8
#define NM (N_*M_)

// ws layout:
//   [0)        int bbox[NM][4] (ymin,ymax,xmin,xmax)
//   [4096)     float boxes_feat[NM][4]
//   [8192)     uint8 masks_small[NM][48*48]            (ends at 598016)
//   [1<<20)    float featT[N][HWF][C]  (n,hw,c)        27 MB
#define WS_BBOX_OFF   0
#define WS_BF_OFF     4096
#define WS_MS_OFF     8192
#define WS_FEATT_OFF  (1u<<20)
#define MS_PER_MAP    (HF*WF)   // 2304

#define VEC4_PER_MAP  (HI*WI/4)                       // 147456
#define SCAN_LPT      16                              // float4 loads per thread
#define SCAN_BX       (VEC4_PER_MAP/(256*SCAN_LPT))   // 36

typedef float f32x4 __attribute__((ext_vector_type(4)));

__global__ void init_ws_kernel(int* __restrict__ bbox, unsigned int* __restrict__ ms32) {
    int idx = blockIdx.x * 256 + threadIdx.x;
    int total32 = NM * MS_PER_MAP / 4;   // 147456
    if (idx < total32) ms32[idx] = 0u;
    if (idx < NM) {
        bbox[idx*4 + 0] = 1 << 30;   // ymin sentinel
        bbox[idx*4 + 1] = -1;        // ymax
        bbox[idx*4 + 2] = 1 << 30;   // xmin
        bbox[idx*4 + 3] = -1;        // xmax
    }
}

// Transpose feat (n,c,hw) -> featT (n,hw,c). 64x64 LDS tile, conflict-free.
__global__ void transpose_feat_kernel(const float* __restrict__ feat,
                                      float* __restrict__ featT) {
    __shared__ float lds[64][65];
    const int n   = blockIdx.z;
    const int hw0 = blockIdx.y * 64;
    const int c0  = blockIdx.x * 64;
    const int t   = threadIdx.x;
    const int lane = t & 63;
    const int grp  = t >> 6;        // 0..3

    #pragma unroll
    for (int i = 0; i < 16; ++i) {
        const int c_l = i * 4 + grp;
        lds[c_l][lane] = feat[((size_t)(n * C_ + c0 + c_l)) * HWF + hw0 + lane];
    }
    __syncthreads();
    #pragma unroll
    for (int i = 0; i < 16; ++i) {
        const int hw_l = i * 4 + grp;
        featT[((size_t)(n * HWF + hw0 + hw_l)) * C_ + c0 + lane] = lds[lane][hw_l];
    }
}

// Phase 1: stream the 604MB mask tensor once (nontemporal — zero reuse).
// window(15) < stride(16) => each nonzero pixel maps to at most one
// masks_small cell: i=(y+7)>>4 valid iff (y&15)!=8 && i<48.
__global__ void scan_masks_kernel(const f32x4* __restrict__ masks,
                                  int* __restrict__ bbox,
                                  unsigned char* __restrict__ msmall) {
    const int nm = blockIdx.y;
    const size_t map_off = (size_t)nm * VEC4_PER_MAP;
    const int chunk = blockIdx.x * (256 * SCAN_LPT);
    int* bb = bbox + nm * 4;
    unsigned char* ms = msmall + nm * MS_PER_MAP;

    #pragma unroll
    for (int k = 0; k < SCAN_LPT; ++k) {
        const int t = chunk + k * 256 + threadIdx.x;
        const f32x4 v = __builtin_nontemporal_load(masks + map_off + t);
        if (v.x > 0.f || v.y > 0.f || v.z > 0.f || v.w > 0.f) {
            const int y  = t / (WI/4);
            const int x4 = (t - y * (WI/4)) * 4;
            const float vv[4] = {v.x, v.y, v.z, v.w};
            #pragma unroll
            for (int q = 0; q < 4; ++q) {
                if (vv[q] > 0.f) {
                    const int x = x4 + q;
                    atomicMin(&bb[0], y);
                    atomicMax(&bb[1], y);
                    atomicMin(&bb[2], x);
                    atomicMax(&bb[3], x);
                    const int i = (y + 7) >> 4;
                    const int j = (x + 7) >> 4;
                    if (((y & 15) != 8) && i < HF && ((x & 15) != 8) && j < WF)
                        ms[i*WF + j] = 1;
                }
            }
        }
    }
}

// Phase 2a: boxes (output 0) + roi_masks (output 1) + boxes_feat (ws).
// One wave (64 threads) per (n,m).
__global__ void boxes_masks_kernel(const int* __restrict__ bbox,
                                   const unsigned char* __restrict__ msmall,
                                   float* __restrict__ boxes_feat,
                                   float* __restrict__ out) {
    const int nm = blockIdx.x;
    const int tid = threadIdx.x;   // 0..63
    const int ymin = bbox[nm*4+0], ymax = bbox[nm*4+1];
    const int xmin = bbox[nm*4+2], xmax = bbox[nm*4+3];

    float bf0, bf1, bf2, bf3;
    if (ymax < 0) {              // empty mask
        bf0 = bf1 = bf2 = bf3 = 0.f;
    } else {
        // dilate(+-7) + expand(+-1) + clip == +-8 clipped; *(Hf/Hi) = /16 exact
        bf0 = (float)max(xmin - 8, 0) * 0.0625f;
        bf1 = (float)max(ymin - 8, 0) * 0.0625f;
        bf2 = (float)min(xmax + 8, WI - 1) * 0.0625f;
        bf3 = (float)min(ymax + 8, HI - 1) * 0.0625f;
    }
    if (tid == 0) {
        boxes_feat[nm*4+0] = bf0; boxes_feat[nm*4+1] = bf1;
        boxes_feat[nm*4+2] = bf2; boxes_feat[nm*4+3] = bf3;
        out[nm*4+0] = bf0 * (1.f/HF);
        out[nm*4+1] = bf1 * (1.f/HF);
        out[nm*4+2] = bf2 * (1.f/HF);
        out[nm*4+3] = bf3 * (1.f/HF);
    }

    // roi_masks crop
    const int x1i = max((int)floorf(bf0), 0);
    const int y1i = max((int)floorf(bf1), 0);
    const int x2i = min((int)floorf(bf2), WF - 1);
    const int y2i = min((int)floorf(bf3), HF - 1);
    const int h = y2i - y1i + 1;
    const int w = x2i - x1i + 1;
    const int r = tid >> 3, s = tid & 7;
    const int yi = y1i + (r * h) / R_;
    const int xi = x1i + (s * w) / R_;
    const float cv = (float)msmall[nm*MS_PER_MAP + yi*WF + xi];
    const bool nonzero = __any(cv > 0.f);
    out[NM*4 + nm*64 + tid] = nonzero ? cv : 1.f;
}

// Phase 2b: roi-align + mask-multiply -> emb (output 2), from featT (n,hw,c).
// Block = 256 threads handles (nm, 64-channel chunk): lanes run along c so
// all bilinear loads are coalesced; LDS tile transposes to coalesced stores.
__global__ void roi_feat_kernel(const float* __restrict__ featT,
                                const float* __restrict__ boxes_feat,
                                const float* __restrict__ roi_masks,
                                float* __restrict__ emb) {
    const int nm = blockIdx.y;
    const int n  = nm >> 6;
    const int c0 = blockIdx.x * 64;
    const int tid = threadIdx.x;

    __shared__ float s_w[4][64];
    __shared__ int   s_a[4][64];
    __shared__ float s_m[64];
    __shared__ float tile[64][65];

    if (tid < 64) {
        const float x1  = boxes_feat[nm*4+0];
        const float y1f = boxes_feat[nm*4+1];
        const float x2  = boxes_feat[nm*4+2];
        const float y2f = boxes_feat[nm*4+3];
        const float bw = fmaxf(x2 - x1, 1.f) * (1.f / R_);
        const float bh = fmaxf(y2f - y1f, 1.f) * (1.f / R_);
        const int r = tid >> 3, s = tid & 7;
        float py = y1f + ((float)r + 0.5f) * bh;
        float px = x1  + ((float)s + 0.5f) * bw;
        py = fminf(fmaxf(py, 0.f), (float)(HF - 1));
        px = fminf(fmaxf(px, 0.f), (float)(WF - 1));
        const int y0 = (int)floorf(py);
        const int x0 = (int)floorf(px);
        const int y1i = min(y0 + 1, HF - 1);
        const int x1i = min(x0 + 1, WF - 1);
        const float ly = py - (float)y0, lx = px - (float)x0;
        const float hy = 1.f - ly,       hx = 1.f - lx;
        s_w[0][tid] = hy * hx;  s_w[1][tid] = hy * lx;
        s_w[2][tid] = ly * hx;  s_w[3][tid] = ly * lx;
        s_a[0][tid] = y0 * WF + x0;   s_a[1][tid] = y0 * WF + x1i;
        s_a[2][tid] = y1i * WF + x0;  s_a[3][tid] = y1i * WF + x1i;
        s_m[tid] = roi_masks[nm * 64 + tid];
    }
    __syncthreads();

    const int c_l = tid & 63;
    const int pg  = tid >> 6;       // 0..3, 16 positions each
    const float* fb = featT + (size_t)n * HWF * C_ + c0 + c_l;
    #pragma unroll
    for (int p = 0; p < 16; ++p) {
        const int pos = pg * 16 + p;
        const float v = s_w[0][pos] * fb[(size_t)s_a[0][pos] * C_]
                      + s_w[1][pos] * fb[(size_t)s_a[1][pos] * C_]
                      + s_w[2][pos] * fb[(size_t)s_a[2][pos] * C_]
                      + s_w[3][pos] * fb[(size_t)s_a[3][pos] * C_];
        tile[pos][c_l] = v;
    }
    __syncthreads();

    const int pos = tid & 63;
    #pragma unroll
    for (int i = 0; i < 16; ++i) {
        const int cc = i * 4 + (tid >> 6);
        emb[((size_t)nm * C_ + c0 + cc) * 64 + pos] = tile[pos][cc] * s_m[pos];
    }
}

extern "C" void kernel_launch(void* const* d_in, const int* in_sizes, int n_in,
                              void* d_out, int out_size, void* d_ws, size_t ws_size,
                              hipStream_t stream) {
    const float* feat  = (const float*)d_in[0];   // (4,768,48,48)
    const float* masks = (const float*)d_in[1];   // (4,64,768,768)
    float* out = (float*)d_out;

    char* ws = (char*)d_ws;
    int* bbox             = (int*)(ws + WS_BBOX_OFF);
    float* boxes_feat     = (float*)(ws + WS_BF_OFF);
    unsigned char* msmall = (unsigned char*)(ws + WS_MS_OFF);
    float* featT          = (float*)(ws + WS_FEATT_OFF);

    // init (bbox sentinels + msmall zero)
    init_ws_kernel<<<(NM*MS_PER_MAP/4 + 255)/256, 256, 0, stream>>>(bbox, (unsigned int*)msmall);

    // feat -> featT (independent of masks)
    dim3 gt(C_/64, HWF/64, N_);   // (12, 36, 4)
    transpose_feat_kernel<<<gt, 256, 0, stream>>>(feat, featT);

    // phase 1: stream masks
    dim3 g1(SCAN_BX, NM);   // (36, 256)
    scan_masks_kernel<<<g1, 256, 0, stream>>>((const f32x4*)masks, bbox, msmall);

    // phase 2a: boxes + roi_masks (one wave per nm)
    boxes_masks_kernel<<<NM, 64, 0, stream>>>(bbox, msmall, boxes_feat, out);

    // phase 2b: emb
    const float* roi_masks = out + NM*4;
    float* emb = out + NM*4 + NM*R_*R_;
    dim3 g2(C_/64, NM);     // (12, 256)
    roi_feat_kernel<<<g2, 256, 0, stream>>>(featT, boxes_feat, roi_masks, emb);
}